// Round 6
// baseline (532.397 us; speedup 1.0000x reference)
//
#include <hip/hip_runtime.h>
#include <stdint.h>

// Problem constants (fixed by reference): T=512, B=256, H=256, 3H=768.
// Pipeline (R6):
//   prep_weights: Wi,Wh (fp32 [256][768]) -> WiT,WhT (bf16 [768][256]).
//   gi_gemm:      R3 structure (LDS A-stage dbuf, reg prefetch across chunks,
//                 48 Wi frags resident, packed direct epilogue) + RAW BARRIER
//                 (lgkmcnt-only). __syncthreads' implicit vmcnt(0) was draining
//                 the next-chunk A prefetch and GI stores at every barrier --
//                 the prefetch never actually overlapped (R3=178, R5 direct-load
//                 variant=207 both latency-bound at <17% HBM).
//   gru_scan:     reset-segment-parallel scan, 16 slots/wg, 48 Wh frags fully
//                 register-resident, direct per-lane packed-GI loads (R5-verified)
//                 prefetched one iteration ahead, RAW BARRIER per iteration
//                 (out[] stores + GI loads free-run across it; only LDS h-state
//                 needs barrier visibility), __launch_bounds__(512,1) so the
//                 ~280-reg demand fits the 2-wave/SIMD 512-reg budget without
//                 scratch spills ((512,2) capped at 256 -> in-loop spills).
// GI layout: t-major packed pairs. uint idx ((t*256+b)*384 + g*128 + wv*16+n16)
//   = {lo: col wv*32+n16, hi: col wv*32+16+n16} of gate g.
// MFMA 16x16x32 bf16 layouts (HW-verified):
//   A[m=lane&15][k=quad*8+j], B[k=quad*8+j][n=lane&15], C/D[row=quad*4+reg][col=lane&15]

typedef __attribute__((ext_vector_type(8))) __bf16 bf16x8;
typedef __attribute__((ext_vector_type(4))) float f32x4;

// Raw workgroup barrier: LDS visibility only. Deliberately NOT __syncthreads():
// that emits s_waitcnt vmcnt(0) expcnt(0) lgkmcnt(0) and force-drains global
// prefetch loads + scattered output stores every iteration.
#define BAR_LGKM() asm volatile("s_waitcnt lgkmcnt(0)\n\ts_barrier" ::: "memory")

__device__ __forceinline__ float bf2f(unsigned short u) {
    union { unsigned int i; float f; } v; v.i = ((unsigned int)u) << 16; return v.f;
}
__device__ __forceinline__ unsigned short f2bf(float f) {
    union { float f; unsigned int i; } v; v.f = f;
    unsigned int x = v.i;
    x = x + 0x7fffu + ((x >> 16) & 1u);   // RNE
    return (unsigned short)(x >> 16);
}
__device__ __forceinline__ float fsig(float x) {
    return __builtin_amdgcn_rcpf(1.f + __builtin_amdgcn_exp2f(-1.442695041f * x));
}
__device__ __forceinline__ float ftanh(float x) {
    return 1.f - 2.f * __builtin_amdgcn_rcpf(1.f + __builtin_amdgcn_exp2f(2.885390082f * x));
}

// ---------------------------------------------------------------- prep
__global__ void prep_weights(const float* __restrict__ Wi, const float* __restrict__ Wh,
                             unsigned short* __restrict__ WiT, unsigned short* __restrict__ WhT) {
    const int idx = blockIdx.x * 256 + threadIdx.x;          // [0, 196608)
    const float* src = blockIdx.y ? Wh : Wi;
    unsigned short* dst = blockIdx.y ? WhT : WiT;
    const int c = idx >> 8, k = idx & 255;
    dst[c * 256 + k] = f2bf(src[k * 768 + c]);
}

// ---------------------------------------------------------------- kernel 1: GI = ins@Wi + bi
// 256 wgs x 512 thr; 32 chunks of 16 t-major rows; LDS A-stage (dbuf) with
// cross-chunk register prefetch; one raw barrier per chunk.
__launch_bounds__(512, 1)
__global__ void gi_gemm(const float* __restrict__ ins, const unsigned short* __restrict__ WiT,
                        const float* __restrict__ bi, unsigned int* __restrict__ GI32) {
    __shared__ unsigned short a_buf[2][16 * 264];   // dbuf: 16 rows x (256+8) bf16

    const int tid = threadIdx.x;
    const int lane = tid & 63, wv = tid >> 6;       // 8 waves
    const int quad = lane >> 4, n16 = lane & 15;

    // Wi B-fragments: wave owns hidden cols [32wv,32wv+32) of each gate (r,z,n)
    bf16x8 wfrag[3][2][8];
#pragma unroll
    for (int g = 0; g < 3; ++g)
#pragma unroll
        for (int tl = 0; tl < 2; ++tl) {
            const int c = g * 256 + wv * 32 + tl * 16 + n16;
            const unsigned short* src = WiT + c * 256 + quad * 8;
#pragma unroll
            for (int kt = 0; kt < 8; ++kt)
                wfrag[g][tl][kt] = *(const bf16x8*)(src + kt * 32);
        }
    float bi_r[3][2];
#pragma unroll
    for (int g = 0; g < 3; ++g)
#pragma unroll
        for (int tl = 0; tl < 2; ++tl)
            bi_r[g][tl] = bi[g * 256 + wv * 32 + tl * 16 + n16];

    const int srow = tid >> 5;        // staging row 0..15
    const int scol = (tid & 31) * 8;  // staging col

    float4 p0, p1;
    {
        const float* p = ins + (size_t)blockIdx.x * 16 * 256 + tid * 8;
        p0 = *(const float4*)p; p1 = *(const float4*)(p + 4);
    }

    int buf = 0;
    for (int i = 0; i < 32; ++i) {
        const int chunk = blockIdx.x + i * 256;  // 16 consecutive t-major rows
        // stage current chunk (prefetched last iteration) into LDS as bf16
        {
            bf16x8 av;
            av[0] = (__bf16)p0.x; av[1] = (__bf16)p0.y; av[2] = (__bf16)p0.z; av[3] = (__bf16)p0.w;
            av[4] = (__bf16)p1.x; av[5] = (__bf16)p1.y; av[6] = (__bf16)p1.z; av[7] = (__bf16)p1.w;
            *(bf16x8*)(&a_buf[buf][srow * 264 + scol]) = av;
        }
        if (i + 1 < 32) {  // prefetch next chunk; stays IN FLIGHT across the raw barrier
            const float* p = ins + (size_t)(blockIdx.x + (i + 1) * 256) * 16 * 256 + tid * 8;
            p0 = *(const float4*)p; p1 = *(const float4*)(p + 4);
        }
        BAR_LGKM();   // LDS visibility only; no vmcnt drain

        f32x4 acc[3][2] = {};
#pragma unroll
        for (int kt = 0; kt < 8; ++kt) {
            bf16x8 af = *(const bf16x8*)(&a_buf[buf][n16 * 264 + kt * 32 + quad * 8]);
#pragma unroll
            for (int g = 0; g < 3; ++g)
#pragma unroll
                for (int tl = 0; tl < 2; ++tl)
                    acc[g][tl] = __builtin_amdgcn_mfma_f32_16x16x32_bf16(af, wfrag[g][tl][kt], acc[g][tl], 0, 0, 0);
        }
        // packed epilogue (R3-verified): 16 consecutive GI rows, full 128-B lines;
        // stores free-run across subsequent barriers.
        {
            const int t = chunk >> 4;
            const int b0 = (chunk & 15) * 16;
#pragma unroll
            for (int g = 0; g < 3; ++g)
#pragma unroll
                for (int r = 0; r < 4; ++r) {
                    const unsigned int lo = f2bf(acc[g][0][r] + bi_r[g][0]);
                    const unsigned int hi = f2bf(acc[g][1][r] + bi_r[g][1]);
                    GI32[((size_t)t * 256 + b0 + quad * 4 + r) * 384 + g * 128 + wv * 16 + n16] =
                        lo | (hi << 16);
                }
        }
        buf ^= 1;
    }
}

// ---------------------------------------------------------------- kernel 2: segment-parallel GRU scan
// slot = quad*4+r owns window [slot*32, slot*32+32); processes [start,end]
// consecutively. t_cur[r] uniform per quad -> per-lane direct packed-GI loads,
// prefetched one full iteration ahead; raw barrier per iteration.
__launch_bounds__(512, 1)
__global__ void gru_scan(const unsigned short* __restrict__ GI, const int* __restrict__ resets,
                         const float* __restrict__ carry, const unsigned short* __restrict__ WhT,
                         const float* __restrict__ bhn, float* __restrict__ out) {
    __shared__ int s_reset[512];                    //  2,048 B
    __shared__ unsigned short s_h[2][16 * 264];     // 16,896 B (h bf16, A-operand, dbuf)

    const int b = blockIdx.x;
    const int tid = threadIdx.x;
    const int lane = tid & 63, wv = tid >> 6;
    const int quad = lane >> 4, n16 = lane & 15;

    s_reset[tid] = resets[tid * 256 + b];

    // Wh B-fragments: all 48 register-resident ((512,1) -> 512-reg budget, no spill)
    bf16x8 wfrag[3][2][8];
#pragma unroll
    for (int g = 0; g < 3; ++g)
#pragma unroll
        for (int tl = 0; tl < 2; ++tl) {
            const int c = g * 256 + wv * 32 + tl * 16 + n16;
            const unsigned short* src = WhT + c * 256 + quad * 8;
#pragma unroll
            for (int kt = 0; kt < 8; ++kt)
                wfrag[g][tl][kt] = *(const bf16x8*)(src + kt * 32);
        }
    float bhn_r[2];
    bhn_r[0] = bhn[wv * 32 + n16];
    bhn_r[1] = bhn[wv * 32 + 16 + n16];

    BAR_LGKM();   // s_reset visible

    // per-slot [start, end] from the reset pattern (verified logic)
    int t_cur[4], t_end[4];
    float h_prev[2][4];
#pragma unroll
    for (int r = 0; r < 4; ++r) {
        const int slot = quad * 4 + r;
        const int w0 = slot * 32;
        int st = -1;
        for (int t = w0; t < w0 + 32; ++t)
            if (t == 0 || s_reset[t] != 0) { st = t; break; }
        int en = 511;
        for (int t = w0 + 32; t < 512; ++t)
            if (s_reset[t] != 0) { en = t - 1; break; }
        float h0 = 0.f, h1 = 0.f;
        if (st == 0 && s_reset[0] == 0) {   // faithful: initial carry when t=0 not reset
            h0 = carry[b * 256 + wv * 32 + n16];
            h1 = carry[b * 256 + wv * 32 + 16 + n16];
        }
        if (st < 0) { t_cur[r] = 1; t_end[r] = 0; }   // dead slot
        else        { t_cur[r] = st; t_end[r] = en; }
        h_prev[0][r] = h0; h_prev[1][r] = h1;
        s_h[0][slot * 264 + wv * 32 + n16] = f2bf(h0);
        s_h[0][slot * 264 + wv * 32 + 16 + n16] = f2bf(h1);
    }

    // direct GI access: lane's 3 packed uints per slot-row (t_cur uniform per quad)
    const unsigned int* GI32b = (const unsigned int*)GI + (size_t)b * 384 + (wv * 16 + n16);
    unsigned int gva[4][3], gvb[4][3];
#pragma unroll
    for (int r = 0; r < 4; ++r) {
        const int tr0 = (t_cur[r] <= t_end[r]) ? t_cur[r] : 0;
        const unsigned int* gp = GI32b + (size_t)tr0 * 98304;
        gva[r][0] = gp[0]; gva[r][1] = gp[128]; gva[r][2] = gp[256];
    }

    BAR_LGKM();   // s_h[0] init (all waves' columns) visible before first MFMA read

#define SCAN_STEP(GCUR, GNXT)                                                                   \
    {                                                                                           \
        const bool any_ = (t_cur[0] <= t_end[0]) | (t_cur[1] <= t_end[1]) |                     \
                          (t_cur[2] <= t_end[2]) | (t_cur[3] <= t_end[3]);                      \
        if (__ballot((int)any_) == 0ull) break;                                                 \
        /* A) prefetch next-iteration GI rows (t+1) -> registers; these stay    */              \
        /*    in flight across the raw barrier and are waited only at next use. */              \
        _Pragma("unroll")                                                                       \
        for (int r = 0; r < 4; ++r) {                                                           \
            const int trn = (t_cur[r] < t_end[r]) ? (t_cur[r] + 1) : 0;                         \
            const unsigned int* gp = GI32b + (size_t)trn * 98304;                               \
            GNXT[r][0] = gp[0]; GNXT[r][1] = gp[128]; GNXT[r][2] = gp[256];                     \
        }                                                                                       \
        /* B) gh = h @ Wh for all 16 slots */                                                   \
        f32x4 acc2[3][2] = {};                                                                  \
        _Pragma("unroll")                                                                       \
        for (int kt = 0; kt < 8; ++kt) {                                                        \
            bf16x8 af = *(const bf16x8*)(&s_h[buf][n16 * 264 + kt * 32 + quad * 8]);            \
            _Pragma("unroll")                                                                   \
            for (int g = 0; g < 3; ++g)                                                         \
                _Pragma("unroll")                                                               \
                for (int tl = 0; tl < 2; ++tl)                                                  \
                    acc2[g][tl] = __builtin_amdgcn_mfma_f32_16x16x32_bf16(af, wfrag[g][tl][kt], acc2[g][tl], 0, 0, 0); \
        }                                                                                       \
        /* C) gates + h update + output (stores free-run across barriers) */                    \
        float hn[2][4];                                                                         \
        _Pragma("unroll")                                                                       \
        for (int r = 0; r < 4; ++r) {                                                           \
            const bool alive = t_cur[r] <= t_end[r];                                            \
            const unsigned int ur = GCUR[r][0], uz = GCUR[r][1], un = GCUR[r][2];               \
            _Pragma("unroll")                                                                   \
            for (int tl = 0; tl < 2; ++tl) {                                                    \
                const int c = wv * 32 + tl * 16 + n16;                                          \
                const float gr = bf2f((unsigned short)(tl ? (ur >> 16) : (ur & 0xffffu)));      \
                const float gz = bf2f((unsigned short)(tl ? (uz >> 16) : (uz & 0xffffu)));      \
                const float gn = bf2f((unsigned short)(tl ? (un >> 16) : (un & 0xffffu)));      \
                const float rr = fsig(gr + acc2[0][tl][r]);                                     \
                const float zz = fsig(gz + acc2[1][tl][r]);                                     \
                const float nn = ftanh(gn + rr * (acc2[2][tl][r] + bhn_r[tl]));                 \
                hn[tl][r] = (1.f - zz) * nn + zz * h_prev[tl][r];                               \
                if (alive) out[((size_t)t_cur[r] * 256 + b) * 256 + c] = hn[tl][r];             \
            }                                                                                   \
        }                                                                                       \
        /* D) advance + write h for next iteration */                                           \
        _Pragma("unroll")                                                                       \
        for (int r = 0; r < 4; ++r) {                                                           \
            const int slot = quad * 4 + r;                                                      \
            const bool alive = t_cur[r] <= t_end[r];                                            \
            const int tn = t_cur[r] + 1;                                                        \
            const bool nalive = alive && (tn <= t_end[r]);                                      \
            float k0 = 0.f, k1 = 0.f;                                                           \
            if (nalive && s_reset[tn & 511] == 0) { k0 = hn[0][r]; k1 = hn[1][r]; }             \
            h_prev[0][r] = k0; h_prev[1][r] = k1;                                               \
            s_h[buf ^ 1][slot * 264 + wv * 32 + n16] = f2bf(k0);                                \
            s_h[buf ^ 1][slot * 264 + wv * 32 + 16 + n16] = f2bf(k1);                           \
            if (alive) t_cur[r] = tn;                                                           \
        }                                                                                       \
        BAR_LGKM();   /* LDS h-state visibility only; no vmcnt drain */                         \
        buf ^= 1;                                                                               \
    }

    int buf = 0;
    for (int it2 = 0; it2 < 260; ++it2) {
        SCAN_STEP(gva, gvb)
        SCAN_STEP(gvb, gva)
    }
#undef SCAN_STEP
}

// ---------------------------------------------------------------- launch
extern "C" void kernel_launch(void* const* d_in, const int* in_sizes, int n_in,
                              void* d_out, int out_size, void* d_ws, size_t ws_size,
                              hipStream_t stream) {
    const float* ins   = (const float*)d_in[0];
    const int* resets  = (const int*)d_in[1];
    const float* carry = (const float*)d_in[2];
    const float* Wi    = (const float*)d_in[3];
    const float* bi    = (const float*)d_in[4];
    const float* Wh    = (const float*)d_in[5];
    const float* bhn   = (const float*)d_in[6];
    float* out = (float*)d_out;

    unsigned short* WiT = (unsigned short*)d_ws;        // [768][256] bf16
    unsigned short* WhT = WiT + 196608;                 // [768][256] bf16
    unsigned short* GI  = WhT + 196608;                 // [512][256][perm 768] bf16 (t-major, packed pairs)

    prep_weights<<<dim3(768, 2), dim3(256), 0, stream>>>(Wi, Wh, WiT, WhT);
    gi_gemm<<<dim3(256), dim3(512), 0, stream>>>(ins, WiT, bi, (unsigned int*)GI);
    gru_scan<<<dim3(256), dim3(512), 0, stream>>>(GI, resets, carry, WhT, bhn, out);
}

// Round 7
// 437.284 us; speedup vs baseline: 1.2175x; 1.2175x over previous
//
#include <hip/hip_runtime.h>
#include <stdint.h>

// Problem constants (fixed by reference): T=512, B=256, H=256, 3H=768.
// Pipeline (R7 = R3 verified structures + raw lgkm-only barriers + gi 2 blocks/CU):
//   prep_weights: Wi,Wh (fp32 [256][768]) -> WiT,WhT (bf16 [768][256]).
//   gi_gemm:      R3 structure (LDS A-stage dbuf, cross-chunk reg prefetch, 48 Wi
//                 frags reg/AGPR-resident, packed direct epilogue). CHANGES: grid
//                 512 (16 chunks/block -> 2 blocks/CU, latency overlap; R6's
//                 (512,1) dropped to 1/CU) and BAR_LGKM instead of __syncthreads
//                 (no vmcnt drain of A-prefetch + GI stores at each barrier).
//   gru_scan:     R3 structure verbatim (181 us measured): 16 slots/wg, 48 Wh
//                 frags reg/AGPR-resident, wave-cooperative contiguous s_gi row
//                 staging (R5/R6's per-lane scattered GI loads caused FETCH
//                 113->297 MB and 181->287 us -- reverted), reg prefetch one
//                 iteration ahead. ONE change: BAR_LGKM per iteration, so out[]
//                 store acks + in-flight GI prefetch are not drained at barriers.
// GI layout: t-major packed pairs. uint idx ((t*256+b)*384 + g*128 + wv*16+n16)
//   = {lo: col wv*32+n16, hi: col wv*32+16+n16} of gate g.
// MFMA 16x16x32 bf16 layouts (HW-verified):
//   A[m=lane&15][k=quad*8+j], B[k=quad*8+j][n=lane&15], C/D[row=quad*4+reg][col=lane&15]

typedef __attribute__((ext_vector_type(8))) __bf16 bf16x8;
typedef __attribute__((ext_vector_type(4))) float f32x4;

// Raw workgroup barrier: LDS visibility only (lgkmcnt drain + arrival).
// Deliberately NOT __syncthreads(): that emits s_waitcnt vmcnt(0) expcnt(0)
// lgkmcnt(0), force-draining global prefetch loads and output-store acks.
#define BAR_LGKM() asm volatile("s_waitcnt lgkmcnt(0)\n\ts_barrier" ::: "memory")

__device__ __forceinline__ float bf2f(unsigned short u) {
    union { unsigned int i; float f; } v; v.i = ((unsigned int)u) << 16; return v.f;
}
__device__ __forceinline__ unsigned short f2bf(float f) {
    union { float f; unsigned int i; } v; v.f = f;
    unsigned int x = v.i;
    x = x + 0x7fffu + ((x >> 16) & 1u);   // RNE
    return (unsigned short)(x >> 16);
}
__device__ __forceinline__ float fsig(float x) {
    return __builtin_amdgcn_rcpf(1.f + __builtin_amdgcn_exp2f(-1.442695041f * x));
}
__device__ __forceinline__ float ftanh(float x) {
    return 1.f - 2.f * __builtin_amdgcn_rcpf(1.f + __builtin_amdgcn_exp2f(2.885390082f * x));
}

// ---------------------------------------------------------------- prep
__global__ void prep_weights(const float* __restrict__ Wi, const float* __restrict__ Wh,
                             unsigned short* __restrict__ WiT, unsigned short* __restrict__ WhT) {
    const int idx = blockIdx.x * 256 + threadIdx.x;          // [0, 196608)
    const float* src = blockIdx.y ? Wh : Wi;
    unsigned short* dst = blockIdx.y ? WhT : WiT;
    const int c = idx >> 8, k = idx & 255;
    dst[c * 256 + k] = f2bf(src[k * 768 + c]);
}

// ---------------------------------------------------------------- kernel 1: GI = ins@Wi + bi
// 512 wgs x 512 thr (2 blocks/CU); 16 chunks of 16 t-major rows each; LDS
// A-stage (dbuf) with cross-chunk register prefetch; one raw barrier per chunk.
__launch_bounds__(512, 2)
__global__ void gi_gemm(const float* __restrict__ ins, const unsigned short* __restrict__ WiT,
                        const float* __restrict__ bi, unsigned int* __restrict__ GI32) {
    __shared__ unsigned short a_buf[2][16 * 264];   // dbuf: 16 rows x (256+8) bf16

    const int tid = threadIdx.x;
    const int lane = tid & 63, wv = tid >> 6;       // 8 waves
    const int quad = lane >> 4, n16 = lane & 15;

    // Wi B-fragments: wave owns hidden cols [32wv,32wv+32) of each gate (r,z,n)
    bf16x8 wfrag[3][2][8];
#pragma unroll
    for (int g = 0; g < 3; ++g)
#pragma unroll
        for (int tl = 0; tl < 2; ++tl) {
            const int c = g * 256 + wv * 32 + tl * 16 + n16;
            const unsigned short* src = WiT + c * 256 + quad * 8;
#pragma unroll
            for (int kt = 0; kt < 8; ++kt)
                wfrag[g][tl][kt] = *(const bf16x8*)(src + kt * 32);
        }
    float bi_r[3][2];
#pragma unroll
    for (int g = 0; g < 3; ++g)
#pragma unroll
        for (int tl = 0; tl < 2; ++tl)
            bi_r[g][tl] = bi[g * 256 + wv * 32 + tl * 16 + n16];

    const int srow = tid >> 5;        // staging row 0..15
    const int scol = (tid & 31) * 8;  // staging col

    float4 p0, p1;
    {
        const float* p = ins + (size_t)blockIdx.x * 16 * 256 + tid * 8;
        p0 = *(const float4*)p; p1 = *(const float4*)(p + 4);
    }

    int buf = 0;
    for (int i = 0; i < 16; ++i) {
        const int chunk = blockIdx.x + i * 512;  // 16 consecutive t-major rows
        // stage current chunk (prefetched last iteration) into LDS as bf16
        {
            bf16x8 av;
            av[0] = (__bf16)p0.x; av[1] = (__bf16)p0.y; av[2] = (__bf16)p0.z; av[3] = (__bf16)p0.w;
            av[4] = (__bf16)p1.x; av[5] = (__bf16)p1.y; av[6] = (__bf16)p1.z; av[7] = (__bf16)p1.w;
            *(bf16x8*)(&a_buf[buf][srow * 264 + scol]) = av;
        }
        if (i + 1 < 16) {  // prefetch next chunk; stays in flight across the raw barrier
            const float* p = ins + (size_t)(blockIdx.x + (i + 1) * 512) * 16 * 256 + tid * 8;
            p0 = *(const float4*)p; p1 = *(const float4*)(p + 4);
        }
        BAR_LGKM();   // LDS visibility only; no vmcnt drain

        f32x4 acc[3][2] = {};
#pragma unroll
        for (int kt = 0; kt < 8; ++kt) {
            bf16x8 af = *(const bf16x8*)(&a_buf[buf][n16 * 264 + kt * 32 + quad * 8]);
#pragma unroll
            for (int g = 0; g < 3; ++g)
#pragma unroll
                for (int tl = 0; tl < 2; ++tl)
                    acc[g][tl] = __builtin_amdgcn_mfma_f32_16x16x32_bf16(af, wfrag[g][tl][kt], acc[g][tl], 0, 0, 0);
        }
        // packed epilogue (R3-verified): 16 consecutive GI rows, full 128-B lines;
        // stores free-run across subsequent barriers.
        {
            const int t = chunk >> 4;
            const int b0 = (chunk & 15) * 16;
#pragma unroll
            for (int g = 0; g < 3; ++g)
#pragma unroll
                for (int r = 0; r < 4; ++r) {
                    const unsigned int lo = f2bf(acc[g][0][r] + bi_r[g][0]);
                    const unsigned int hi = f2bf(acc[g][1][r] + bi_r[g][1]);
                    GI32[((size_t)t * 256 + b0 + quad * 4 + r) * 384 + g * 128 + wv * 16 + n16] =
                        lo | (hi << 16);
                }
        }
        buf ^= 1;
    }
}

// ---------------------------------------------------------------- kernel 2: segment-parallel GRU scan
// slot = quad*4+r owns window [slot*32, slot*32+32); processes [start,end]
// consecutively. Wave-cooperative contiguous s_gi row staging (R3-verified),
// speculative t+1 rows prefetched to regs at iteration top, drained to
// s_gi[buf^1] after compute; one raw barrier per iteration.
__launch_bounds__(512, 2)
__global__ void gru_scan(const unsigned short* __restrict__ GI, const int* __restrict__ resets,
                         const float* __restrict__ carry, const unsigned short* __restrict__ WhT,
                         const float* __restrict__ bhn, float* __restrict__ out) {
    __shared__ int s_reset[512];                    //  2,048 B
    __shared__ unsigned short s_h[2][16 * 264];     // 16,896 B (h bf16, A-operand, dbuf)
    __shared__ unsigned int s_gi[2][16 * 386];      // 49,408 B (gi rows, packed uints, dbuf)

    const int b = blockIdx.x;
    const int tid = threadIdx.x;
    const int lane = tid & 63, wv = tid >> 6;
    const int quad = lane >> 4, n16 = lane & 15;

    s_reset[tid] = resets[tid * 256 + b];

    // Wh B-fragments (reg/AGPR-resident for the whole scan; R0/R3-verified)
    bf16x8 wfrag[3][2][8];
#pragma unroll
    for (int g = 0; g < 3; ++g)
#pragma unroll
        for (int tl = 0; tl < 2; ++tl) {
            const int c = g * 256 + wv * 32 + tl * 16 + n16;
            const unsigned short* src = WhT + c * 256 + quad * 8;
#pragma unroll
            for (int kt = 0; kt < 8; ++kt)
                wfrag[g][tl][kt] = *(const bf16x8*)(src + kt * 32);
        }
    float bhn_r[2];
    bhn_r[0] = bhn[wv * 32 + n16];
    bhn_r[1] = bhn[wv * 32 + 16 + n16];

    BAR_LGKM();   // s_reset visible

    // per-slot [start, end] from the reset pattern (verified logic)
    int t_cur[4], t_end[4];
    float h_prev[2][4];
#pragma unroll
    for (int r = 0; r < 4; ++r) {
        const int slot = quad * 4 + r;
        const int w0 = slot * 32;
        int st = -1;
        for (int t = w0; t < w0 + 32; ++t)
            if (t == 0 || s_reset[t] != 0) { st = t; break; }
        int en = 511;
        for (int t = w0 + 32; t < 512; ++t)
            if (s_reset[t] != 0) { en = t - 1; break; }
        float h0 = 0.f, h1 = 0.f;
        if (st == 0 && s_reset[0] == 0) {   // faithful: initial carry when t=0 not reset
            h0 = carry[b * 256 + wv * 32 + n16];
            h1 = carry[b * 256 + wv * 32 + 16 + n16];
        }
        if (st < 0) { t_cur[r] = 1; t_end[r] = 0; }   // dead slot
        else        { t_cur[r] = st; t_end[r] = en; }
        h_prev[0][r] = h0; h_prev[1][r] = h1;
        s_h[0][slot * 264 + wv * 32 + n16] = f2bf(h0);
        s_h[0][slot * 264 + wv * 32 + 16 + n16] = f2bf(h1);
    }

    const int srcl = (wv >> 1) * 16;   // lane whose quad tracks this wave's 2 slots
    const unsigned short* gbase = GI + (size_t)b * 768;

    // prologue: stage iteration-0 rows into s_gi[0] (contiguous 1536-B rows)
    {
        int c0 = (t_cur[0] <= t_end[0]) ? t_cur[0] : 0;
        int c1 = (t_cur[1] <= t_end[1]) ? t_cur[1] : 0;
        int c2 = (t_cur[2] <= t_end[2]) ? t_cur[2] : 0;
        int c3 = (t_cur[3] <= t_end[3]) ? t_cur[3] : 0;
        const int v0 = __builtin_amdgcn_readlane(c0, srcl);
        const int v1 = __builtin_amdgcn_readlane(c1, srcl);
        const int v2 = __builtin_amdgcn_readlane(c2, srcl);
        const int v3 = __builtin_amdgcn_readlane(c3, srcl);
        const int r0 = (wv & 1) ? v2 : v0;
        const int r1 = (wv & 1) ? v3 : v1;
        const uint2* s0 = (const uint2*)(gbase + (size_t)r0 * 196608) + lane * 3;
        const uint2* s1 = (const uint2*)(gbase + (size_t)r1 * 196608) + lane * 3;
        uint2* d0 = (uint2*)(&s_gi[0][(2 * wv) * 386]) + lane * 3;
        uint2* d1 = (uint2*)(&s_gi[0][(2 * wv + 1) * 386]) + lane * 3;
        d0[0] = s0[0]; d0[1] = s0[1]; d0[2] = s0[2];
        d1[0] = s1[0]; d1[1] = s1[1]; d1[2] = s1[2];
    }
    BAR_LGKM();   // s_h[0] init + s_gi[0] visible before first MFMA/gates read

    int buf = 0;
    for (int it = 0; it < 520; ++it) {
        const bool any = (t_cur[0] <= t_end[0]) | (t_cur[1] <= t_end[1]) |
                         (t_cur[2] <= t_end[2]) | (t_cur[3] <= t_end[3]);
        if (__ballot((int)any) == 0ull) break;   // uniform: all waves track all 16 slots

        // A) speculative prefetch of next-iteration rows (t+1) -> registers;
        //    stays in flight across compute, waited (vmcnt) only at E.
        uint2 pf0a, pf0b, pf0c, pf1a, pf1b, pf1c;
        {
            int s0_ = (t_cur[0] < t_end[0]) ? t_cur[0] + 1 : 0;
            int s1_ = (t_cur[1] < t_end[1]) ? t_cur[1] + 1 : 0;
            int s2_ = (t_cur[2] < t_end[2]) ? t_cur[2] + 1 : 0;
            int s3_ = (t_cur[3] < t_end[3]) ? t_cur[3] + 1 : 0;
            const int v0 = __builtin_amdgcn_readlane(s0_, srcl);
            const int v1 = __builtin_amdgcn_readlane(s1_, srcl);
            const int v2 = __builtin_amdgcn_readlane(s2_, srcl);
            const int v3 = __builtin_amdgcn_readlane(s3_, srcl);
            const int r0 = (wv & 1) ? v2 : v0;
            const int r1 = (wv & 1) ? v3 : v1;
            const uint2* s0 = (const uint2*)(gbase + (size_t)r0 * 196608) + lane * 3;
            const uint2* s1 = (const uint2*)(gbase + (size_t)r1 * 196608) + lane * 3;
            pf0a = s0[0]; pf0b = s0[1]; pf0c = s0[2];
            pf1a = s1[0]; pf1b = s1[1]; pf1c = s1[2];
        }

        // B) gh = h @ Wh for all 16 slots (overlaps the prefetch latency)
        f32x4 acc2[3][2] = {};
#pragma unroll
        for (int kt = 0; kt < 8; ++kt) {
            bf16x8 af = *(const bf16x8*)(&s_h[buf][n16 * 264 + kt * 32 + quad * 8]);
#pragma unroll
            for (int g = 0; g < 3; ++g)
#pragma unroll
                for (int tl = 0; tl < 2; ++tl)
                    acc2[g][tl] = __builtin_amdgcn_mfma_f32_16x16x32_bf16(af, wfrag[g][tl][kt], acc2[g][tl], 0, 0, 0);
        }

        // C) gates + h update + output (stores free-run across barriers)
        float hn[2][4];
#pragma unroll
        for (int r = 0; r < 4; ++r) {
            const bool alive = t_cur[r] <= t_end[r];
            const unsigned int* gp = &s_gi[buf][(quad * 4 + r) * 386 + wv * 16 + n16];
            const unsigned int ur = gp[0], uz = gp[128], un = gp[256];
#pragma unroll
            for (int tl = 0; tl < 2; ++tl) {
                const int c = wv * 32 + tl * 16 + n16;
                const float gr = bf2f((unsigned short)(tl ? (ur >> 16) : (ur & 0xffffu)));
                const float gz = bf2f((unsigned short)(tl ? (uz >> 16) : (uz & 0xffffu)));
                const float gn = bf2f((unsigned short)(tl ? (un >> 16) : (un & 0xffffu)));
                const float rr = fsig(gr + acc2[0][tl][r]);
                const float zz = fsig(gz + acc2[1][tl][r]);
                const float nn = ftanh(gn + rr * (acc2[2][tl][r] + bhn_r[tl]));
                hn[tl][r] = (1.f - zz) * nn + zz * h_prev[tl][r];
                if (alive) out[((size_t)t_cur[r] * 256 + b) * 256 + c] = hn[tl][r];
            }
        }

        // D) advance + write h for next iteration
#pragma unroll
        for (int r = 0; r < 4; ++r) {
            const int slot = quad * 4 + r;
            const bool alive = t_cur[r] <= t_end[r];
            const int tn = t_cur[r] + 1;
            const bool nalive = alive && (tn <= t_end[r]);
            float k0 = 0.f, k1 = 0.f;
            if (nalive && s_reset[tn & 511] == 0) { k0 = hn[0][r]; k1 = hn[1][r]; }
            h_prev[0][r] = k0; h_prev[1][r] = k1;
            s_h[buf ^ 1][slot * 264 + wv * 32 + n16] = f2bf(k0);
            s_h[buf ^ 1][slot * 264 + wv * 32 + 16 + n16] = f2bf(k1);
            if (alive) t_cur[r] = tn;
        }

        // E) drain prefetch regs -> s_gi[buf^1] (vmcnt wait auto-inserted here)
        {
            uint2* d0 = (uint2*)(&s_gi[buf ^ 1][(2 * wv) * 386]) + lane * 3;
            uint2* d1 = (uint2*)(&s_gi[buf ^ 1][(2 * wv + 1) * 386]) + lane * 3;
            d0[0] = pf0a; d0[1] = pf0b; d0[2] = pf0c;
            d1[0] = pf1a; d1[1] = pf1b; d1[2] = pf1c;
        }
        BAR_LGKM();   // LDS visibility only; out-stores + any in-flight loads free-run
        buf ^= 1;
    }
}

// ---------------------------------------------------------------- launch
extern "C" void kernel_launch(void* const* d_in, const int* in_sizes, int n_in,
                              void* d_out, int out_size, void* d_ws, size_t ws_size,
                              hipStream_t stream) {
    const float* ins   = (const float*)d_in[0];
    const int* resets  = (const int*)d_in[1];
    const float* carry = (const float*)d_in[2];
    const float* Wi    = (const float*)d_in[3];
    const float* bi    = (const float*)d_in[4];
    const float* Wh    = (const float*)d_in[5];
    const float* bhn   = (const float*)d_in[6];
    float* out = (float*)d_out;

    unsigned short* WiT = (unsigned short*)d_ws;        // [768][256] bf16
    unsigned short* WhT = WiT + 196608;                 // [768][256] bf16
    unsigned short* GI  = WhT + 196608;                 // [512][256][perm 768] bf16 (t-major, packed pairs)

    prep_weights<<<dim3(768, 2), dim3(256), 0, stream>>>(Wi, Wh, WiT, WhT);
    gi_gemm<<<dim3(512), dim3(512), 0, stream>>>(ins, WiT, bi, (unsigned int*)GI);
    gru_scan<<<dim3(256), dim3(512), 0, stream>>>(GI, resets, carry, WhT, bhn, out);
}